// Round 1
// baseline (416.719 us; speedup 1.0000x reference)
//
#include <hip/hip_runtime.h>

#define NEG_SLOPE 0.2f
#define BN_EPS 1e-5f

// ---------------------------------------------------------------------------
// K1: xl = x @ W^T  (N x 64, K=64), plus per-node attention scalars
//     s_i[n] = <xl[n], att_i> + <emb[n], att_em_i>
//     s_j[n] = <xl[n], att_j> + <emb[n], att_em_j>
// One wave per row; W^T staged in LDS (conflict-free: consecutive lanes).
// ---------------------------------------------------------------------------
__global__ void k_lin(const float* __restrict__ x, const float* __restrict__ W,
                      const float* __restrict__ emb,
                      const float* __restrict__ att_i, const float* __restrict__ att_j,
                      const float* __restrict__ att_em_i, const float* __restrict__ att_em_j,
                      float* __restrict__ xl, float* __restrict__ s_i, float* __restrict__ s_j,
                      int N) {
    __shared__ float Wt[64 * 64];  // Wt[k][c] = W[c][k]
    int tid = threadIdx.x;  // 256 threads
    for (int t = tid; t < 4096; t += 256) {
        int c = t >> 6, k = t & 63;
        Wt[k * 64 + c] = W[t];
    }
    __syncthreads();
    int lane = tid & 63;
    int wave = tid >> 6;
    int gwave = blockIdx.x * (blockDim.x >> 6) + wave;
    int stride = gridDim.x * (blockDim.x >> 6);
    for (int r = gwave; r < N; r += stride) {
        float xr = x[r * 64 + lane];
        float acc = 0.f;
#pragma unroll
        for (int k = 0; k < 64; ++k) {
            float xk = __shfl(xr, k, 64);
            acc = fmaf(xk, Wt[k * 64 + lane], acc);
        }
        xl[r * 64 + lane] = acc;
        float e = emb[r * 64 + lane];
        float vi = fmaf(acc, att_i[lane], e * att_em_i[lane]);
        float vj = fmaf(acc, att_j[lane], e * att_em_j[lane]);
#pragma unroll
        for (int o = 32; o; o >>= 1) {
            vi += __shfl_down(vi, o, 64);
            vj += __shfl_down(vj, o, 64);
        }
        if (lane == 0) { s_i[r] = vi; s_j[r] = vj; }
    }
}

// ---------------------------------------------------------------------------
// K2: histogram of dst
// ---------------------------------------------------------------------------
__global__ void k_count(const int* __restrict__ dst, int E, int* __restrict__ counts) {
    int i = blockIdx.x * blockDim.x + threadIdx.x;
    if (i < E) atomicAdd(&counts[dst[i]], 1);
}

// ---------------------------------------------------------------------------
// K3: single-block exclusive scan over counts[0..N) -> offsets[0..N]
// Wave-level shfl scans; ~3 barriers per 1024-chunk.
// ---------------------------------------------------------------------------
__global__ void k_scan(const int* __restrict__ counts, int N, int* __restrict__ offsets) {
    __shared__ int wexcl[16];
    __shared__ int ctot;
    __shared__ int carry;
    int tid = threadIdx.x;  // 1024
    int lane = tid & 63, w = tid >> 6;
    if (tid == 0) carry = 0;
    __syncthreads();
    for (int base = 0; base < N; base += 1024) {
        int i = base + tid;
        int v = (i < N) ? counts[i] : 0;
        int incl = v;
#pragma unroll
        for (int o = 1; o < 64; o <<= 1) {
            int t = __shfl_up(incl, o, 64);
            if (lane >= o) incl += t;
        }
        if (lane == 63) wexcl[w] = incl;
        __syncthreads();
        if (w == 0) {
            int s = (lane < 16) ? wexcl[lane] : 0;
            int si = s;
#pragma unroll
            for (int o = 1; o < 16; o <<= 1) {
                int t = __shfl_up(si, o, 64);
                if (lane >= o) si += t;
            }
            if (lane < 16) wexcl[lane] = si - s;  // exclusive wave offset
            if (lane == 15) ctot = si;            // chunk total
        }
        __syncthreads();
        if (i < N) offsets[i] = carry + wexcl[w] + (incl - v);
        __syncthreads();
        if (tid == 0) carry += ctot;
        __syncthreads();
    }
    if (tid == 0) offsets[N] = carry;
}

// ---------------------------------------------------------------------------
// K4: scatter edges into CSR order by dst
// ---------------------------------------------------------------------------
__global__ void k_scatter(const int* __restrict__ src, const int* __restrict__ dst, int E,
                          const int* __restrict__ offsets, int* __restrict__ cursor,
                          int* __restrict__ csr_src) {
    int e = blockIdx.x * blockDim.x + threadIdx.x;
    if (e < E) {
        int d = dst[e];
        int p = atomicAdd(&cursor[d], 1);
        csr_src[offsets[d] + p] = src[e];
    }
}

// ---------------------------------------------------------------------------
// K5: per-node softmax attention + aggregation. One wave per node,
// lane = channel. Self-loop handled implicitly. First 64 edges' (j, a)
// cached in registers from the max pass and rebroadcast via shfl.
// ---------------------------------------------------------------------------
__global__ void k_aggregate(const float* __restrict__ xl, const float* __restrict__ s_i,
                            const float* __restrict__ s_j, const int* __restrict__ offsets,
                            const int* __restrict__ csr_src, const float* __restrict__ bias,
                            float* __restrict__ pre, int N) {
    int lane = threadIdx.x & 63;
    int gwave = blockIdx.x * (blockDim.x >> 6) + (threadIdx.x >> 6);
    int stride = gridDim.x * (blockDim.x >> 6);
    for (int i = gwave; i < N; i += stride) {
        int base = offsets[i];
        int deg = offsets[i + 1] - base;
        float sii = s_i[i];
        float a_self = sii + s_j[i];
        a_self = a_self >= 0.f ? a_self : NEG_SLOPE * a_self;
        // pass 1: max over edges (edge-parallel over lanes), cache first 64
        float m = a_self;
        int jreg = 0;
        float areg = 0.f;
        bool first = true;
        for (int e = lane; e < deg; e += 64) {
            int j = csr_src[base + e];
            float a = sii + s_j[j];
            a = a >= 0.f ? a : NEG_SLOPE * a;
            if (first) { jreg = j; areg = a; first = false; }
            m = fmaxf(m, a);
        }
#pragma unroll
        for (int o = 32; o; o >>= 1) m = fmaxf(m, __shfl_xor(m, o, 64));
        // pass 2: exp + accumulate (channel-parallel over lanes)
        float w_self = __expf(a_self - m);
        float denom = w_self;
        float acc = w_self * xl[i * 64 + lane];
        int lim = deg < 64 ? deg : 64;
        for (int e = 0; e < lim; ++e) {
            int j = __shfl(jreg, e, 64);
            float a = __shfl(areg, e, 64);
            float wgt = __expf(a - m);
            denom += wgt;
            acc = fmaf(wgt, xl[j * 64 + lane], acc);
        }
        for (int e = 64; e < deg; ++e) {
            int j = csr_src[base + e];
            float a = sii + s_j[j];
            a = a >= 0.f ? a : NEG_SLOPE * a;
            float wgt = __expf(a - m);
            denom += wgt;
            acc = fmaf(wgt, xl[j * 64 + lane], acc);
        }
        pre[i * 64 + lane] = acc / (denom + 1e-16f) + bias[lane];
    }
}

// ---------------------------------------------------------------------------
// K6: BN batch-stat partials (sum, sumsq per channel)
// ---------------------------------------------------------------------------
__global__ void k_stats(const float* __restrict__ pre, int N, float* __restrict__ sums) {
    int lane = threadIdx.x & 63, w = threadIdx.x >> 6;
    int gwave = blockIdx.x * (blockDim.x >> 6) + w;
    int stride = gridDim.x * (blockDim.x >> 6);
    float s = 0.f, q = 0.f;
    for (int r = gwave; r < N; r += stride) {
        float v = pre[r * 64 + lane];
        s += v;
        q = fmaf(v, v, q);
    }
    __shared__ float ls[4][64], lq[4][64];
    ls[w][lane] = s;
    lq[w][lane] = q;
    __syncthreads();
    if (w == 0) {
        s = ls[0][lane] + ls[1][lane] + ls[2][lane] + ls[3][lane];
        q = lq[0][lane] + lq[1][lane] + lq[2][lane] + lq[3][lane];
        atomicAdd(&sums[lane], s);
        atomicAdd(&sums[64 + lane], q);
    }
}

// ---------------------------------------------------------------------------
// K7: finalize BN affine params: scale/shift per channel
// ---------------------------------------------------------------------------
__global__ void k_bnparam(const float* __restrict__ sums, const float* __restrict__ gamma,
                          const float* __restrict__ beta, int N, float* __restrict__ scsh) {
    int c = threadIdx.x;  // 64
    float invN = 1.f / (float)N;
    float mu = sums[c] * invN;
    float var = sums[64 + c] * invN - mu * mu;
    float sc = gamma[c] * rsqrtf(var + BN_EPS);
    scsh[c] = sc;
    scsh[64 + c] = beta[c] - mu * sc;
}

// ---------------------------------------------------------------------------
// K8: normalize + ReLU (in-place on d_out)
// ---------------------------------------------------------------------------
__global__ void k_norm(const float* __restrict__ pre, const float* __restrict__ scsh,
                       float* __restrict__ out, int total) {
    int i = blockIdx.x * blockDim.x + threadIdx.x;
    if (i < total) {
        int c = i & 63;
        float v = fmaf(pre[i], scsh[c], scsh[64 + c]);
        out[i] = fmaxf(v, 0.f);
    }
}

extern "C" void kernel_launch(void* const* d_in, const int* in_sizes, int n_in,
                              void* d_out, int out_size, void* d_ws, size_t ws_size,
                              hipStream_t stream) {
    const float* x        = (const float*)d_in[0];
    const int*   ei       = (const int*)d_in[1];
    const float* emb      = (const float*)d_in[2];
    const float* W        = (const float*)d_in[3];
    const float* att_i    = (const float*)d_in[4];
    const float* att_j    = (const float*)d_in[5];
    const float* att_em_i = (const float*)d_in[6];
    const float* att_em_j = (const float*)d_in[7];
    const float* bias     = (const float*)d_in[8];
    const float* gamma    = (const float*)d_in[9];
    const float* beta     = (const float*)d_in[10];

    int N = in_sizes[0] / 64;
    int E = in_sizes[1] / 2;
    const int* srcv = ei;
    const int* dstv = ei + E;

    char* ws = (char*)d_ws;
    size_t o = 0;
    auto alloc = [&](size_t bytes) -> char* {
        char* p = ws + o;
        o += bytes;
        o = (o + 255) & ~(size_t)255;
        return p;
    };
    float* xl      = (float*)alloc((size_t)N * 64 * 4);
    float* s_i     = (float*)alloc((size_t)N * 4);
    float* s_j     = (float*)alloc((size_t)N * 4);
    int*   offsets = (int*)alloc((size_t)(N + 1) * 4);
    int*   counts  = (int*)alloc((size_t)N * 4);
    int*   cursor  = (int*)alloc((size_t)N * 4);
    int*   csr_src = (int*)alloc((size_t)E * 4);
    float* sums    = (float*)alloc(128 * 4);
    float* scsh    = (float*)alloc(128 * 4);
    float* pre     = (float*)d_out;  // pre-BN output lives in d_out; k_norm is in-place

    hipMemsetAsync(counts, 0, (size_t)N * 4, stream);
    hipMemsetAsync(cursor, 0, (size_t)N * 4, stream);
    hipMemsetAsync(sums, 0, 128 * 4, stream);

    k_lin<<<512, 256, 0, stream>>>(x, W, emb, att_i, att_j, att_em_i, att_em_j,
                                   xl, s_i, s_j, N);
    k_count<<<(E + 255) / 256, 256, 0, stream>>>(dstv, E, counts);
    k_scan<<<1, 1024, 0, stream>>>(counts, N, offsets);
    k_scatter<<<(E + 255) / 256, 256, 0, stream>>>(srcv, dstv, E, offsets, cursor, csr_src);
    k_aggregate<<<1024, 256, 0, stream>>>(xl, s_i, s_j, offsets, csr_src, bias, pre, N);
    k_stats<<<256, 256, 0, stream>>>(pre, N, sums);
    k_bnparam<<<1, 64, 0, stream>>>(sums, gamma, beta, N, scsh);
    int total = N * 64;
    k_norm<<<(total + 255) / 256, 256, 0, stream>>>(pre, scsh, (float*)d_out, total);
}